// Round 10
// baseline (5434.048 us; speedup 1.0000x reference)
//
#include <hip/hip_runtime.h>
#include <hip/hip_bf16.h>

#define B_   32
#define T_   512
#define NN_  16
#define CV_  150
#define D_   512
#define H_   512
#define BT_  16384      // B*T
#define K0_  1024       // 2*D
#define G3H_ 1536       // 3*H
#define NBF_ 160        // 5 * 32 GRU blocks
#define GXB_ 6144       // 24 * 256 fused xp-GEMM blocks
#define XSLOT_ 16384    // elems per x ring slot (32*512)
#define XRING_ 32
#define HRING_ 8
#define SENT32 0x7f7f7f7fu
#define HCAP 16384
#define XCAP 16384
#define BCAP 65536

using bf16x8 = __attribute__((ext_vector_type(8))) short;
using f32x4  = __attribute__((ext_vector_type(4))) float;
using u32x4  = __attribute__((ext_vector_type(4))) unsigned int;
typedef unsigned long long u64;

__device__ __forceinline__ unsigned short f2bf(float f){
  unsigned int u = __builtin_bit_cast(unsigned int, f);
  u += 0x7fffu + ((u >> 16) & 1u);           // RNE
  return (unsigned short)(u >> 16);
}

__device__ __forceinline__ void store8(unsigned short* p, f32x4 a, f32x4 b){
  union { unsigned short us[8]; u32x4 v; } u;
  u.us[0]=f2bf(a[0]); u.us[1]=f2bf(a[1]); u.us[2]=f2bf(a[2]); u.us[3]=f2bf(a[3]);
  u.us[4]=f2bf(b[0]); u.us[5]=f2bf(b[1]); u.us[6]=f2bf(b[2]); u.us[7]=f2bf(b[3]);
  *(u32x4*)p = u.v;
}

// agent-scope (device-coherent) helpers: relaxed atomics, no fences (proven r0/r3/r6-r9)
__device__ __forceinline__ u64 ld_coh_u64(const u64* p){
  return __hip_atomic_load(p, __ATOMIC_RELAXED, __HIP_MEMORY_SCOPE_AGENT);
}
__device__ __forceinline__ void st_coh_u32(void* p, unsigned int v){
  __hip_atomic_store((unsigned int*)p, v, __ATOMIC_RELAXED, __HIP_MEMORY_SCOPE_AGENT);
}
__device__ __forceinline__ float ld_coh_f32(const float* p){
  return __hip_atomic_load(p, __ATOMIC_RELAXED, __HIP_MEMORY_SCOPE_AGENT);
}
__device__ __forceinline__ void st_coh_f32(float* p, float v){
  __hip_atomic_store((unsigned int*)p, __builtin_bit_cast(unsigned int, v),
                     __ATOMIC_RELAXED, __HIP_MEMORY_SCOPE_AGENT);
}
__device__ __forceinline__ void st_flag(int* p, int v){
  __hip_atomic_store(p, v, __ATOMIC_RELAXED, __HIP_MEMORY_SCOPE_AGENT);
}
__device__ __forceinline__ int ld_flag(const int* p){
  return __hip_atomic_load(p, __ATOMIC_RELAXED, __HIP_MEMORY_SCOPE_AGENT);
}

__device__ __forceinline__ bool bad64(u64 q){
  return ((unsigned int)q == SENT32) | ((unsigned int)(q >> 32) == SENT32);
}

// ---------------- fp32 -> bf16 weight conversion ----------------
__global__ void convert_bf16(const float* __restrict__ src,
                             unsigned short* __restrict__ dst, int n){
  int i = blockIdx.x * 256 + threadIdx.x;
  if (i < n) dst[i] = f2bf(src[i]);
}

// ---------------- embeddings ----------------
__global__ __launch_bounds__(64) void emb_kernel(
    const int* __restrict__ note, const int* __restrict__ chord,
    const float* __restrict__ ctab, const float* __restrict__ ntab,
    unsigned short* __restrict__ x0){
  const int bt = blockIdx.x;
  const int tid = threadIdx.x;
  __shared__ int sn[NN_];
  if (tid < NN_) sn[tid] = note[bt * NN_ + tid];
  __syncthreads();
  float alive = 1.f, cnt = 0.f;
  float msk[NN_];
  #pragma unroll
  for (int k = 0; k < NN_; ++k){ if (sn[k] == 0) alive = 0.f; msk[k] = alive; cnt += alive; }
  const float inv = 1.f / fmaxf(cnt, 1.f);
  const int ch = chord[bt];
  const int d0 = tid * 8;
  f32x4 c0 = {0.f,0.f,0.f,0.f}, c1 = {0.f,0.f,0.f,0.f};
  if (ch != 0){
    const float* cp = ctab + (size_t)ch * D_ + d0;
    c0 = *(const f32x4*)cp; c1 = *(const f32x4*)(cp + 4);
  }
  f32x4 s0 = {0.f,0.f,0.f,0.f}, s1 = {0.f,0.f,0.f,0.f};
  #pragma unroll
  for (int k = 0; k < NN_; ++k){
    if (msk[k] != 0.f){
      const float* np = ntab + (size_t)sn[k] * D_ + d0;
      s0 += *(const f32x4*)np;
      s1 += *(const f32x4*)(np + 4);
    }
  }
  s0 *= inv; s1 *= inv;
  unsigned short* o = x0 + (size_t)bt * K0_ + d0;
  store8(o, c0, c1);
  store8(o + D_, s0, s1);
}

// ---------------- bf16 MFMA GEMM:  Y = X[M,K] @ W[N,K]^T + bias ----------------
__global__ __launch_bounds__(256) void gemm_bt(
    const unsigned short* __restrict__ X, const unsigned short* __restrict__ W,
    const float* __restrict__ bias, float* __restrict__ Y,
    int M, int N, int K, int wmode){
  const int lane = threadIdx.x & 63;
  const int wave = threadIdx.x >> 6;
  const int l15 = lane & 15, kq4 = lane >> 4;
  const int m_frag = blockIdx.y * 64 + wave * 16 + l15;
  const int n_base = blockIdx.x * 64;
  f32x4 acc[4] = {{0.f,0.f,0.f,0.f},{0.f,0.f,0.f,0.f},{0.f,0.f,0.f,0.f},{0.f,0.f,0.f,0.f}};
  const unsigned short* xptr = X + (size_t)m_frag * K + kq4 * 8;
  const unsigned short* wptr[4];
  #pragma unroll
  for (int i = 0; i < 4; ++i){
    int n = n_base + i * 16 + l15;
    if (n >= N) n = N - 1;
    wptr[i] = W + (size_t)n * K + kq4 * 8;
  }
  for (int k0 = 0; k0 < K; k0 += 32){
    bf16x8 a = *(const bf16x8*)(xptr + k0);
    #pragma unroll
    for (int i = 0; i < 4; ++i){
      bf16x8 b = *(const bf16x8*)(wptr[i] + k0);
      acc[i] = __builtin_amdgcn_mfma_f32_16x16x32_bf16(a, b, acc[i], 0, 0, 0);
    }
  }
  const int mrow = blockIdx.y * 64 + wave * 16 + kq4 * 4;
  #pragma unroll
  for (int i = 0; i < 4; ++i){
    int n = n_base + i * 16 + l15;
    if (n < N){
      float bv = bias[n];
      #pragma unroll
      for (int r = 0; r < 4; ++r){
        int m = mrow + r;
        float v = acc[i][r] + bv;
        if (wmode == 0) Y[(size_t)m * N + n] = v;
        else            Y[((size_t)(m & (T_-1)) * N + n) * B_ + (m >> 9)] = v;
      }
    }
  }
}

// ---------------- fused 5-layer GRU + xp-GEMM ----------------
// Blocks [0,160): GRU role — exchange protocol byte-identical to r8/r9 (proven):
//   h ring hT[l][t&7][b][u]: data at slot t+1, sentinel re-arm at slot t+4.
//   x ring xT[l][t&31][b][u]: data at slot t, re-arm at slot t+16; bp every 4 steps.
//   Per-step order: x-phase first (fills h-store visibility window), then h-phase.
//   In-kernel W swizzle (fp32 -> bf16 A-frags in LDS, hides under startup waits)
//   and in-kernel bias loads (r9-proven). Layer-4 xout via plain stores (r8).
// Blocks [160,160+6144): xp-GEMM role, chunk-major; gprog[tc]==768 marks chunk valid.
// FC runs as a separate trailing launch (r8 structure — r9's fused-FC spinners
// polluted the rendezvous line and cost +220us inside the dispatch).
union Ufrag { u64 q[2]; bf16x8 v; };

__global__ __launch_bounds__(256, 1) void gru_fused(
    float* xp, unsigned short* hT, unsigned short* xT, unsigned short* xout,
    int* cprog, const unsigned short* __restrict__ x0g,
    const unsigned short* __restrict__ wih0g, const float* __restrict__ bih0g,
    int* gprog,
    const float* __restrict__ whh0g, const float* __restrict__ whhrg,
    const float* __restrict__ wihrg, const float* __restrict__ bhh0g,
    const float* __restrict__ bihrg, const float* __restrict__ bhhrg){
  __shared__ unsigned short w_s[96 * 512];     // 96 KB A-frags
  __shared__ float p_s[2][4][2][2][16][16];    // [pb][r,z,hn,xn][myn][kh][u][b] 16KB

  const int tid = threadIdx.x;
  const int blk = blockIdx.x;

  // =========== xp-GEMM role ===========
  if (blk >= NBF_){
    const int idx = blk - NBF_;
    const int gx  = idx % 24;            // n tile
    const int gyy = idx / 24;            // [0,256)
    const int bb  = gyy & 31, tc = gyy >> 5;
    const int m0  = bb * 512 + tc * 64;
    const int lane = tid & 63, wave = tid >> 6;
    const int l15 = lane & 15, kq4 = lane >> 4;
    const int m_frag = m0 + wave * 16 + l15;
    const int n_base = gx * 64;
    f32x4 acc[4] = {{0.f,0.f,0.f,0.f},{0.f,0.f,0.f,0.f},{0.f,0.f,0.f,0.f},{0.f,0.f,0.f,0.f}};
    const unsigned short* xptr = x0g + (size_t)m_frag * K0_ + kq4 * 8;
    const unsigned short* wptr[4];
    #pragma unroll
    for (int i = 0; i < 4; ++i){
      int n = n_base + i * 16 + l15;
      wptr[i] = wih0g + (size_t)n * K0_ + kq4 * 8;
    }
    for (int k0 = 0; k0 < K0_; k0 += 32){
      bf16x8 a = *(const bf16x8*)(xptr + k0);
      #pragma unroll
      for (int i = 0; i < 4; ++i){
        bf16x8 b = *(const bf16x8*)(wptr[i] + k0);
        acc[i] = __builtin_amdgcn_mfma_f32_16x16x32_bf16(a, b, acc[i], 0, 0, 0);
      }
    }
    const int mrow = m0 + wave * 16 + kq4 * 4;
    #pragma unroll
    for (int i = 0; i < 4; ++i){
      int n = n_base + i * 16 + l15;
      float bv = bih0g[n];
      #pragma unroll
      for (int r = 0; r < 4; ++r){
        int m = mrow + r;
        float v = acc[i][r] + bv;
        st_coh_f32(&xp[((size_t)(m & (T_-1)) * G3H_ + n) * B_ + (m >> 9)], v);
      }
    }
    asm volatile("s_waitcnt vmcnt(0)" ::: "memory");
    __syncthreads();                       // all 256 threads' stores drained
    if (tid == 0) atomicAdd(&gprog[tc], 1);
    return;
  }

  // =========== GRU role ===========
  const int l   = blk >> 5;
  const int sub = blk & 31;

  { // in-kernel W swizzle: fp32 global -> bf16 A-frags in LDS (hides under startup)
    #pragma unroll 1
    for (int i = 0; i < 24; ++i){
      int idx = i * 256 + tid;            // [0, 6144)
      int fr = idx >> 6, lam = idx & 63;
      int ks = fr & 31, g = fr >> 5;
      int row = g * 512 + sub * 16 + (lam & 15);
      int kcol = (ks & 15) * 32 + ((lam >> 4) << 3);
      f32x4 a = {0.f,0.f,0.f,0.f}, b2 = {0.f,0.f,0.f,0.f};
      if (l == 0){
        if (ks < 16){
          const float* sp = whh0g + (size_t)row * H_ + kcol;
          a = *(const f32x4*)sp; b2 = *(const f32x4*)(sp + 4);
        }
      } else {
        const float* wbase = (ks < 16) ? whhrg : wihrg;
        const float* sp = wbase + (size_t)(l - 1) * G3H_ * H_ + (size_t)row * H_ + kcol;
        a = *(const f32x4*)sp; b2 = *(const f32x4*)(sp + 4);
      }
      store8(&w_s[fr * 512 + lam * 8], a, b2);
    }
  }
  __syncthreads();

  const int lane = tid & 63, wave = tid >> 6;
  const int l15 = lane & 15, l4 = lane >> 4;
  const int myn = wave >> 1;            // batch 16-group
  const int kh  = wave & 1;             // K-half
  const int myb = (myn << 4) + l15;
  const int fro = (l4 << 3);
  const int khofs = kh * 256;           // element offset of the K-half
  const int khb = kh * 8;               // frag base of the K-half

  const int cb = tid & 31;
  const int cj = (tid >> 5) * 2;
  const int jg = sub * 16 + cj;

  // in-kernel bias (r9-proven)
  float br0, bz0, bx0, bn0, br1, bz1, bx1, bn1;
  if (l == 0){
    br0 = bhh0g[jg];       bz0 = bhh0g[512 + jg];     bx0 = 0.f; bn0 = bhh0g[1024 + jg];
    br1 = bhh0g[jg + 1];   bz1 = bhh0g[512 + jg + 1]; bx1 = 0.f; bn1 = bhh0g[1024 + jg + 1];
  } else {
    const float* bi = bihrg + (size_t)(l - 1) * G3H_;
    const float* bh = bhhrg + (size_t)(l - 1) * G3H_;
    br0 = bi[jg] + bh[jg];           bz0 = bi[512 + jg] + bh[512 + jg];
    bx0 = bi[1024 + jg];             bn0 = bh[1024 + jg];
    br1 = bi[jg + 1] + bh[jg + 1];   bz1 = bi[512 + jg + 1] + bh[512 + jg + 1];
    bx1 = bi[1024 + jg + 1];         bn1 = bh[1024 + jg + 1];
  }
  float hres0 = 0.f, hres1 = 0.f;

  unsigned short* hTl = hT + (size_t)l * (HRING_ * 32 * 512);
  unsigned short* xTw = xT + (size_t)(l < 4 ? l : 0) * ((size_t)XRING_ * XSLOT_);
  const unsigned short* xTr = xT + (size_t)(l > 0 ? l - 1 : 0) * ((size_t)XRING_ * XSLOT_);
  const int* bp_own = cprog + (l << 5);          // consumers of my x publish here
  int*       bp_pub = cprog + ((l > 0 ? l - 1 : 0) << 5);

  // xp 2-ahead prefetch registers (layer 0 only); chunk-0 gate first
  float era=0,eza=0,ena=0,era1=0,eza1=0,ena1=0;
  float erb=0,ezb=0,enb=0,erb1=0,ezb1=0,enb1=0;
  if (l == 0){
    if (tid == 0){
      int itc = 0;
      while (ld_flag(&gprog[0]) < 768){
        if (++itc > (1 << 20)) break;
        __builtin_amdgcn_s_sleep(8);
      }
    }
    __syncthreads();
    { const float* xq = xp + (size_t)0 * (G3H_ * B_) + cb;
      era=ld_coh_f32(&xq[(size_t)(0*H_+jg)*B_]); era1=ld_coh_f32(&xq[(size_t)(0*H_+jg+1)*B_]);
      eza=ld_coh_f32(&xq[(size_t)(1*H_+jg)*B_]); eza1=ld_coh_f32(&xq[(size_t)(1*H_+jg+1)*B_]);
      ena=ld_coh_f32(&xq[(size_t)(2*H_+jg)*B_]); ena1=ld_coh_f32(&xq[(size_t)(2*H_+jg+1)*B_]); }
    { const float* xq = xp + (size_t)1 * (G3H_ * B_) + cb;
      erb=ld_coh_f32(&xq[(size_t)(0*H_+jg)*B_]); erb1=ld_coh_f32(&xq[(size_t)(0*H_+jg+1)*B_]);
      ezb=ld_coh_f32(&xq[(size_t)(1*H_+jg)*B_]); ezb1=ld_coh_f32(&xq[(size_t)(1*H_+jg+1)*B_]);
      enb=ld_coh_f32(&xq[(size_t)(2*H_+jg)*B_]); enb1=ld_coh_f32(&xq[(size_t)(2*H_+jg+1)*B_]); }
  }

  for (int t = 0; t < T_; ++t){
    const int pb = t & 1;

    // ---- issue x(t) loads (produced >=1 skew-steps ago) ----
    Ufrag xb[8];
    const unsigned short* xs = nullptr;
    if (l > 0){
      xs = xTr + (size_t)(t & (XRING_-1)) * XSLOT_ + (size_t)myb * 512 + khofs + fro;
      #pragma unroll
      for (int j = 0; j < 8; ++j){
        const u64* sp = (const u64*)(xs + (j << 5));
        xb[j].q[0] = ld_coh_u64(sp); xb[j].q[1] = ld_coh_u64(sp + 1);
      }
    }

    // ---- issue all h(t) frag loads (early miss -> cheap; real poll is later) ----
    Ufrag hb[8];
    const unsigned short* hf = hTl + (((size_t)(t & (HRING_-1)) * 32 + myb) << 9) + khofs + fro;
    #pragma unroll
    for (int j = 0; j < 8; ++j){
      const u64* sp = (const u64*)(hf + (j << 5));
      hb[j].q[0] = ld_coh_u64(sp); hb[j].q[1] = ld_coh_u64(sp + 1);
    }

    // ---- producer back-pressure (every 4 steps; proven margins) ----
    if (l < 4 && t && (t & 3) == 0){
      int itc = 0;
      while (true){
        int v = (lane < 32) ? ld_flag(&bp_own[lane]) : 0x7fffffff;
        if (__all(v >= t - 4)) break;
        if (++itc > BCAP) break;
        __builtin_amdgcn_s_sleep(2);
      }
    }

    f32x4 accR = {0.f,0.f,0.f,0.f}, accZ = {0.f,0.f,0.f,0.f};
    f32x4 accN = {0.f,0.f,0.f,0.f}, accX = {0.f,0.f,0.f,0.f};

    // ---- x phase FIRST: fills the h-store visibility window with real work ----
    if (l > 0){
      #pragma unroll
      for (int j = 0; j < 8; ++j){
        int itc = 0;
        while (__any((int)(bad64(xb[j].q[0]) | bad64(xb[j].q[1])))){
          if (++itc > XCAP) break;
          if (itc > 2) __builtin_amdgcn_s_sleep(2);
          const u64* sp = (const u64*)(xs + (j << 5));
          xb[j].q[0] = ld_coh_u64(sp); xb[j].q[1] = ld_coh_u64(sp + 1);
        }
        bf16x8 b  = xb[j].v;
        bf16x8 a0 = *(const bf16x8*)&w_s[(0 * 32 + 16 + khb + j) * 512 + lane * 8];
        bf16x8 a1 = *(const bf16x8*)&w_s[(1 * 32 + 16 + khb + j) * 512 + lane * 8];
        bf16x8 a2 = *(const bf16x8*)&w_s[(2 * 32 + 16 + khb + j) * 512 + lane * 8];
        accR = __builtin_amdgcn_mfma_f32_16x16x32_bf16(a0, b, accR, 0, 0, 0);
        accZ = __builtin_amdgcn_mfma_f32_16x16x32_bf16(a1, b, accZ, 0, 0, 0);
        accX = __builtin_amdgcn_mfma_f32_16x16x32_bf16(a2, b, accX, 0, 0, 0);  // xn
      }
    }

    // ---- h phase: incremental poll-and-consume (wait frag j -> 3 MFMAs) ----
    #pragma unroll
    for (int j = 0; j < 8; ++j){
      int itc = 0;
      while (__any((int)(bad64(hb[j].q[0]) | bad64(hb[j].q[1])))){
        if (++itc > HCAP) break;
        if (itc > 2) __builtin_amdgcn_s_sleep(2);
        const u64* sp = (const u64*)(hf + (j << 5));
        hb[j].q[0] = ld_coh_u64(sp); hb[j].q[1] = ld_coh_u64(sp + 1);
      }
      bf16x8 b  = hb[j].v;
      bf16x8 a0 = *(const bf16x8*)&w_s[(0 * 32 + khb + j) * 512 + lane * 8];
      bf16x8 a1 = *(const bf16x8*)&w_s[(1 * 32 + khb + j) * 512 + lane * 8];
      bf16x8 a2 = *(const bf16x8*)&w_s[(2 * 32 + khb + j) * 512 + lane * 8];
      accR = __builtin_amdgcn_mfma_f32_16x16x32_bf16(a0, b, accR, 0, 0, 0);
      accZ = __builtin_amdgcn_mfma_f32_16x16x32_bf16(a1, b, accZ, 0, 0, 0);
      accN = __builtin_amdgcn_mfma_f32_16x16x32_bf16(a2, b, accN, 0, 0, 0);
    }

    // ---- xp chunk gate + prefetch for t+2 (layer 0) ----
    float erc=0,ezc=0,enc=0,erc1=0,ezc1=0,enc1=0;
    if (l == 0){
      if (((t + 2) & 63) == 0){
        const int ck = ((t + 2) & (T_ - 1)) >> 6;
        if (tid == 0){
          int itc = 0;
          while (ld_flag(&gprog[ck]) < 768){
            if (++itc > (1 << 20)) break;
            __builtin_amdgcn_s_sleep(8);
          }
        }
        __syncthreads();
      }
      const float* xq = xp + (size_t)((t + 2) & (T_ - 1)) * (G3H_ * B_) + cb;
      erc=ld_coh_f32(&xq[(size_t)(0*H_+jg)*B_]); erc1=ld_coh_f32(&xq[(size_t)(0*H_+jg+1)*B_]);
      ezc=ld_coh_f32(&xq[(size_t)(1*H_+jg)*B_]); ezc1=ld_coh_f32(&xq[(size_t)(1*H_+jg+1)*B_]);
      enc=ld_coh_f32(&xq[(size_t)(2*H_+jg)*B_]); enc1=ld_coh_f32(&xq[(size_t)(2*H_+jg+1)*B_]);
    }

    // ---- partials -> p_s[pb] ----
    #pragma unroll
    for (int r = 0; r < 4; ++r){
      int u = l4 * 4 + r;
      p_s[pb][0][myn][kh][u][l15] = accR[r];
      p_s[pb][1][myn][kh][u][l15] = accZ[r];
      p_s[pb][2][myn][kh][u][l15] = accN[r];
      p_s[pb][3][myn][kh][u][l15] = accX[r];
    }
    __syncthreads();

    // ---- combine ----
    {
      const int nt = cb >> 4, bc = cb & 15;
      float rp0 = p_s[pb][0][nt][0][cj][bc]   + p_s[pb][0][nt][1][cj][bc];
      float rp1 = p_s[pb][0][nt][0][cj+1][bc] + p_s[pb][0][nt][1][cj+1][bc];
      float zp0 = p_s[pb][1][nt][0][cj][bc]   + p_s[pb][1][nt][1][cj][bc];
      float zp1 = p_s[pb][1][nt][0][cj+1][bc] + p_s[pb][1][nt][1][cj+1][bc];
      float hp0 = p_s[pb][2][nt][0][cj][bc]   + p_s[pb][2][nt][1][cj][bc];
      float hp1 = p_s[pb][2][nt][0][cj+1][bc] + p_s[pb][2][nt][1][cj+1][bc];
      float xq0 = p_s[pb][3][nt][0][cj][bc]   + p_s[pb][3][nt][1][cj][bc];
      float xq1 = p_s[pb][3][nt][0][cj+1][bc] + p_s[pb][3][nt][1][cj+1][bc];
      float r0 = 1.f / (1.f + __expf(-(rp0 + era  + br0)));
      float r1 = 1.f / (1.f + __expf(-(rp1 + era1 + br1)));
      float z0 = 1.f / (1.f + __expf(-(zp0 + eza  + bz0)));
      float z1 = 1.f / (1.f + __expf(-(zp1 + eza1 + bz1)));
      float nx0 = (l > 0) ? (xq0 + bx0) : ena;
      float nx1 = (l > 0) ? (xq1 + bx1) : ena1;
      float e0 = __expf(2.f * (nx0 + r0 * (hp0 + bn0)));
      float e1 = __expf(2.f * (nx1 + r1 * (hp1 + bn1)));
      float n0 = (e0 - 1.f) / (e0 + 1.f);
      float n1 = (e1 - 1.f) / (e1 + 1.f);
      float h0 = (1.f - z0) * n0 + z0 * hres0; hres0 = h0;
      float h1 = (1.f - z1) * n1 + z1 * hres1; hres1 = h1;
      unsigned int pk = (unsigned int)f2bf(h0) | ((unsigned int)f2bf(h1) << 16);

      // h data first (peers are waiting on it), then x data, then sentinels
      st_coh_u32(hTl + (((size_t)((t + 1) & (HRING_-1)) * 32 + cb) << 9) + jg, pk);
      if (l < 4)
        st_coh_u32(xTw + (size_t)(t & (XRING_-1)) * XSLOT_ + (size_t)cb * 512 + jg, pk);
      else
        *(unsigned int*)&xout[((size_t)cb * T_ + t) * H_ + jg] = pk;   // plain (r8)
      st_coh_u32(hTl + (((size_t)((t + 4) & (HRING_-1)) * 32 + cb) << 9) + jg, SENT32);
      if (l < 4)
        st_coh_u32(xTw + (size_t)((t + 16) & (XRING_-1)) * XSLOT_ + (size_t)cb * 512 + jg, SENT32);

      // consumer progress publish (every 4 steps; proven)
      if (l > 0 && (t & 3) == 3 && tid == 0) st_flag(&bp_pub[sub], t);

      // rotate xp prefetch regs
      era = erb; eza = ezb; ena = enb; era1 = erb1; eza1 = ezb1; ena1 = enb1;
      erb = erc; ezb = ezc; enb = enc; erb1 = erc1; ezb1 = ezc1; enb1 = enc1;
    }
  }
}

extern "C" void kernel_launch(void* const* d_in, const int* in_sizes, int n_in,
                              void* d_out, int out_size, void* d_ws, size_t ws_size,
                              hipStream_t stream){
  (void)in_sizes; (void)n_in; (void)out_size; (void)ws_size;
  const int*   note  = (const int*)d_in[0];
  const int*   chord = (const int*)d_in[1];
  const float* ctab  = (const float*)d_in[2];
  const float* ntab  = (const float*)d_in[3];
  const float* wih0  = (const float*)d_in[4];
  const float* whh0  = (const float*)d_in[5];
  const float* bih0  = (const float*)d_in[6];
  const float* bhh0  = (const float*)d_in[7];
  const float* wihr  = (const float*)d_in[8];
  const float* whhr  = (const float*)d_in[9];
  const float* bihr  = (const float*)d_in[10];
  const float* bhhr  = (const float*)d_in[11];
  const float* fcw   = (const float*)d_in[12];
  const float* fcb   = (const float*)d_in[13];
  float* out = (float*)d_out;

  char* ws = (char*)d_ws;
  size_t off = 0;
  auto alloc = [&](size_t bytes)->char*{
    char* p = ws + off; off = (off + bytes + 255) & ~(size_t)255; return p;
  };
  int*            cprog   = (int*)alloc(160 * sizeof(int));
  int*            gprog   = (int*)alloc(8 * sizeof(int));
  float*          xp      = (float*)alloc((size_t)BT_ * G3H_ * 4);        // 100.66 MB
  unsigned short* fcw_b   = (unsigned short*)alloc((size_t)CV_ * H_ * 2); // 0.15 MB
  unsigned short* xout    = (unsigned short*)alloc((size_t)BT_ * H_ * 2); // 16.78 MB
  unsigned short* x0      = (unsigned short*)alloc((size_t)BT_ * K0_ * 2);// 33.55 MB
  unsigned short* wih0_b  = (unsigned short*)alloc((size_t)G3H_ * K0_ * 2);// 3.15 MB
  const size_t hT_bytes = (size_t)5 * HRING_ * 32 * 512 * 2;              // 2.62 MB
  const size_t xT_bytes = (size_t)4 * XRING_ * XSLOT_ * 2;                // 4.19 MB
  unsigned short* hT      = (unsigned short*)alloc(hT_bytes);
  unsigned short* xT      = (unsigned short*)alloc(xT_bytes);
  // total ~161 MB

  hipMemsetAsync(cprog, 0, 160 * sizeof(int), stream);
  hipMemsetAsync(gprog, 0, 8 * sizeof(int), stream);
  hipMemsetAsync(hT, 0x7F, hT_bytes, stream);
  for (int ll = 0; ll < 5; ++ll)   // slot 0 = h(0) = zeros
    hipMemsetAsync(hT + (size_t)ll * (HRING_ * 32 * 512), 0, 32 * 512 * 2, stream);
  hipMemsetAsync(xT, 0x7F, xT_bytes, stream);

  { int n = G3H_ * K0_; convert_bf16<<<(n + 255) / 256, 256, 0, stream>>>(wih0, wih0_b, n); }
  { int n = CV_ * H_;   convert_bf16<<<(n + 255) / 256, 256, 0, stream>>>(fcw, fcw_b, n); }

  emb_kernel<<<BT_, 64, 0, stream>>>(note, chord, ctab, ntab, x0);

  // fused: 160 GRU + 6144 xp-GEMM (chunk-major) blocks in one launch
  gru_fused<<<NBF_ + GXB_, 256, 0, stream>>>(
      xp, hT, xT, xout, cprog, x0, wih0_b, bih0, gprog,
      whh0, whhr, wihr, bhh0, bihr, bhhr);

  // FC: out = xout @ fcw^T + fcb  (separate launch — r8 structure)
  gemm_bt<<<dim3((CV_ + 63) / 64, BT_ / 64), 256, 0, stream>>>(
      xout, fcw_b, fcb, out, BT_, CV_, H_, 0);
}

// Round 11
// 5357.986 us; speedup vs baseline: 1.0142x; 1.0142x over previous
//
#include <hip/hip_runtime.h>
#include <hip/hip_bf16.h>

#define B_   32
#define T_   512
#define NN_  16
#define CV_  150
#define D_   512
#define H_   512
#define BT_  16384      // B*T
#define K0_  1024       // 2*D
#define G3H_ 1536       // 3*H
#define NBF_ 160        // 5 * 32 GRU blocks
#define GXB_ 6144       // 24 * 256 fused xp-GEMM blocks
#define WSZ_ 49152      // bf16 elems of swizzled W per block (96 frags * 512)
#define XSLOT_ 16384    // elems per x ring slot (32*512)
#define XRING_ 32
#define HRING_ 8
#define SENT32 0x7f7f7f7fu
#define HCAP 16384
#define XCAP 16384
#define BCAP 65536

using bf16x8 = __attribute__((ext_vector_type(8))) short;
using f32x4  = __attribute__((ext_vector_type(4))) float;
using u32x4  = __attribute__((ext_vector_type(4))) unsigned int;
typedef unsigned long long u64;

__device__ __forceinline__ unsigned short f2bf(float f){
  unsigned int u = __builtin_bit_cast(unsigned int, f);
  u += 0x7fffu + ((u >> 16) & 1u);           // RNE
  return (unsigned short)(u >> 16);
}

__device__ __forceinline__ void store8(unsigned short* p, f32x4 a, f32x4 b){
  union { unsigned short us[8]; u32x4 v; } u;
  u.us[0]=f2bf(a[0]); u.us[1]=f2bf(a[1]); u.us[2]=f2bf(a[2]); u.us[3]=f2bf(a[3]);
  u.us[4]=f2bf(b[0]); u.us[5]=f2bf(b[1]); u.us[6]=f2bf(b[2]); u.us[7]=f2bf(b[3]);
  *(u32x4*)p = u.v;
}

// agent-scope (device-coherent) helpers: relaxed atomics, no fences (proven r0/r3/r6-r10)
__device__ __forceinline__ u64 ld_coh_u64(const u64* p){
  return __hip_atomic_load(p, __ATOMIC_RELAXED, __HIP_MEMORY_SCOPE_AGENT);
}
__device__ __forceinline__ void st_coh_u32(void* p, unsigned int v){
  __hip_atomic_store((unsigned int*)p, v, __ATOMIC_RELAXED, __HIP_MEMORY_SCOPE_AGENT);
}
__device__ __forceinline__ float ld_coh_f32(const float* p){
  return __hip_atomic_load(p, __ATOMIC_RELAXED, __HIP_MEMORY_SCOPE_AGENT);
}
__device__ __forceinline__ void st_coh_f32(float* p, float v){
  __hip_atomic_store((unsigned int*)p, __builtin_bit_cast(unsigned int, v),
                     __ATOMIC_RELAXED, __HIP_MEMORY_SCOPE_AGENT);
}
__device__ __forceinline__ void st_flag(int* p, int v){
  __hip_atomic_store(p, v, __ATOMIC_RELAXED, __HIP_MEMORY_SCOPE_AGENT);
}
__device__ __forceinline__ int ld_flag(const int* p){
  return __hip_atomic_load(p, __ATOMIC_RELAXED, __HIP_MEMORY_SCOPE_AGENT);
}

__device__ __forceinline__ bool bad64(u64 q){
  return ((unsigned int)q == SENT32) | ((unsigned int)(q >> 32) == SENT32);
}

// ---------------- fp32 -> bf16 weight conversion ----------------
__global__ void convert_bf16(const float* __restrict__ src,
                             unsigned short* __restrict__ dst, int n){
  int i = blockIdx.x * 256 + threadIdx.x;
  if (i < n) dst[i] = f2bf(src[i]);
}

// ---------------- swizzle W into MFMA A-frag layout (r8-proven prep) ----------------
__global__ void prep_wfrag(const float* __restrict__ whh0,
                           const float* __restrict__ whhr,
                           const float* __restrict__ wihr,
                           unsigned short* __restrict__ wsw, int total){
  int idx = blockIdx.x * 256 + threadIdx.x;
  if (idx >= total) return;
  int pos = idx & 511;
  int lam = pos >> 3, e = pos & 7;
  int fr  = idx >> 9;
  int ks  = fr & 31;
  int g   = (fr >> 5) % 3;
  int blk = fr / 96;
  int sub = blk & 31, l = blk >> 5;
  int row = g * 512 + sub * 16 + (lam & 15);
  int k   = (ks & 15) * 32 + (lam >> 4) * 8 + e;
  float v;
  if (l == 0) v = (ks < 16) ? whh0[(size_t)row * H_ + k] : 0.f;
  else {
    const float* w = (ks < 16) ? (whhr + (size_t)(l - 1) * G3H_ * H_)
                               : (wihr + (size_t)(l - 1) * G3H_ * H_);
    v = w[(size_t)row * H_ + k];
  }
  wsw[idx] = f2bf(v);
}

// ---------------- embeddings ----------------
__global__ __launch_bounds__(64) void emb_kernel(
    const int* __restrict__ note, const int* __restrict__ chord,
    const float* __restrict__ ctab, const float* __restrict__ ntab,
    unsigned short* __restrict__ x0){
  const int bt = blockIdx.x;
  const int tid = threadIdx.x;
  __shared__ int sn[NN_];
  if (tid < NN_) sn[tid] = note[bt * NN_ + tid];
  __syncthreads();
  float alive = 1.f, cnt = 0.f;
  float msk[NN_];
  #pragma unroll
  for (int k = 0; k < NN_; ++k){ if (sn[k] == 0) alive = 0.f; msk[k] = alive; cnt += alive; }
  const float inv = 1.f / fmaxf(cnt, 1.f);
  const int ch = chord[bt];
  const int d0 = tid * 8;
  f32x4 c0 = {0.f,0.f,0.f,0.f}, c1 = {0.f,0.f,0.f,0.f};
  if (ch != 0){
    const float* cp = ctab + (size_t)ch * D_ + d0;
    c0 = *(const f32x4*)cp; c1 = *(const f32x4*)(cp + 4);
  }
  f32x4 s0 = {0.f,0.f,0.f,0.f}, s1 = {0.f,0.f,0.f,0.f};
  #pragma unroll
  for (int k = 0; k < NN_; ++k){
    if (msk[k] != 0.f){
      const float* np = ntab + (size_t)sn[k] * D_ + d0;
      s0 += *(const f32x4*)np;
      s1 += *(const f32x4*)(np + 4);
    }
  }
  s0 *= inv; s1 *= inv;
  unsigned short* o = x0 + (size_t)bt * K0_ + d0;
  store8(o, c0, c1);
  store8(o + D_, s0, s1);
}

// ---------------- bf16 MFMA GEMM:  Y = X[M,K] @ W[N,K]^T + bias ----------------
__global__ __launch_bounds__(256) void gemm_bt(
    const unsigned short* __restrict__ X, const unsigned short* __restrict__ W,
    const float* __restrict__ bias, float* __restrict__ Y,
    int M, int N, int K, int wmode){
  const int lane = threadIdx.x & 63;
  const int wave = threadIdx.x >> 6;
  const int l15 = lane & 15, kq4 = lane >> 4;
  const int m_frag = blockIdx.y * 64 + wave * 16 + l15;
  const int n_base = blockIdx.x * 64;
  f32x4 acc[4] = {{0.f,0.f,0.f,0.f},{0.f,0.f,0.f,0.f},{0.f,0.f,0.f,0.f},{0.f,0.f,0.f,0.f}};
  const unsigned short* xptr = X + (size_t)m_frag * K + kq4 * 8;
  const unsigned short* wptr[4];
  #pragma unroll
  for (int i = 0; i < 4; ++i){
    int n = n_base + i * 16 + l15;
    if (n >= N) n = N - 1;
    wptr[i] = W + (size_t)n * K + kq4 * 8;
  }
  for (int k0 = 0; k0 < K; k0 += 32){
    bf16x8 a = *(const bf16x8*)(xptr + k0);
    #pragma unroll
    for (int i = 0; i < 4; ++i){
      bf16x8 b = *(const bf16x8*)(wptr[i] + k0);
      acc[i] = __builtin_amdgcn_mfma_f32_16x16x32_bf16(a, b, acc[i], 0, 0, 0);
    }
  }
  const int mrow = blockIdx.y * 64 + wave * 16 + kq4 * 4;
  #pragma unroll
  for (int i = 0; i < 4; ++i){
    int n = n_base + i * 16 + l15;
    if (n < N){
      float bv = bias[n];
      #pragma unroll
      for (int r = 0; r < 4; ++r){
        int m = mrow + r;
        float v = acc[i][r] + bv;
        if (wmode == 0) Y[(size_t)m * N + n] = v;
        else            Y[((size_t)(m & (T_-1)) * N + n) * B_ + (m >> 9)] = v;
      }
    }
  }
}

// ---------------- fused 5-layer GRU + xp-GEMM (r8 structure, bias in-kernel) --------
// Blocks [0,160): GRU role — exchange protocol byte-identical to r8 (proven 5318us):
//   h ring hT[l][t&7][b][u]: data at slot t+1, sentinel re-arm at slot t+4.
//   x ring xT[l][t&31][b][u]: data at slot t, re-arm at slot t+16; bp every 4 steps.
//   Per-step order: x-phase first (fills h-store visibility window), then h-phase.
//   W from pre-swizzled wsw (r8 — in-kernel fp32 swizzle cost +120us, r10).
//   Bias loaded in-kernel (r9/r10-proven component; replaces prep_bias launch).
// Blocks [160,160+6144): xp-GEMM role, chunk-major; gprog[tc]==768 marks chunk valid.
// FC runs as a separate trailing launch (r8 — fused-FC spinners cost +220us, r9).
union Ufrag { u64 q[2]; bf16x8 v; };

__global__ __launch_bounds__(256, 1) void gru_fused(
    float* xp, const unsigned short* __restrict__ wsw,
    unsigned short* hT, unsigned short* xT, unsigned short* xout,
    int* cprog, const unsigned short* __restrict__ x0g,
    const unsigned short* __restrict__ wih0g, const float* __restrict__ bih0g,
    int* gprog,
    const float* __restrict__ bhh0g, const float* __restrict__ bihrg,
    const float* __restrict__ bhhrg){
  __shared__ unsigned short w_s[96 * 512];     // 96 KB A-frags
  __shared__ float p_s[2][4][2][2][16][16];    // [pb][r,z,hn,xn][myn][kh][u][b] 16KB

  const int tid = threadIdx.x;
  const int blk = blockIdx.x;

  // =========== xp-GEMM role ===========
  if (blk >= NBF_){
    const int idx = blk - NBF_;
    const int gx  = idx % 24;            // n tile
    const int gyy = idx / 24;            // [0,256)
    const int bb  = gyy & 31, tc = gyy >> 5;
    const int m0  = bb * 512 + tc * 64;
    const int lane = tid & 63, wave = tid >> 6;
    const int l15 = lane & 15, kq4 = lane >> 4;
    const int m_frag = m0 + wave * 16 + l15;
    const int n_base = gx * 64;
    f32x4 acc[4] = {{0.f,0.f,0.f,0.f},{0.f,0.f,0.f,0.f},{0.f,0.f,0.f,0.f},{0.f,0.f,0.f,0.f}};
    const unsigned short* xptr = x0g + (size_t)m_frag * K0_ + kq4 * 8;
    const unsigned short* wptr[4];
    #pragma unroll
    for (int i = 0; i < 4; ++i){
      int n = n_base + i * 16 + l15;
      wptr[i] = wih0g + (size_t)n * K0_ + kq4 * 8;
    }
    for (int k0 = 0; k0 < K0_; k0 += 32){
      bf16x8 a = *(const bf16x8*)(xptr + k0);
      #pragma unroll
      for (int i = 0; i < 4; ++i){
        bf16x8 b = *(const bf16x8*)(wptr[i] + k0);
        acc[i] = __builtin_amdgcn_mfma_f32_16x16x32_bf16(a, b, acc[i], 0, 0, 0);
      }
    }
    const int mrow = m0 + wave * 16 + kq4 * 4;
    #pragma unroll
    for (int i = 0; i < 4; ++i){
      int n = n_base + i * 16 + l15;
      float bv = bih0g[n];
      #pragma unroll
      for (int r = 0; r < 4; ++r){
        int m = mrow + r;
        float v = acc[i][r] + bv;
        st_coh_f32(&xp[((size_t)(m & (T_-1)) * G3H_ + n) * B_ + (m >> 9)], v);
      }
    }
    asm volatile("s_waitcnt vmcnt(0)" ::: "memory");
    __syncthreads();                       // all 256 threads' stores drained
    if (tid == 0) atomicAdd(&gprog[tc], 1);
    return;
  }

  // =========== GRU role (exchange protocol byte-identical to r8) ===========
  const int l   = blk >> 5;
  const int sub = blk & 31;

  { // W -> LDS from pre-swizzled wsw (r8)
    const u32x4* src = (const u32x4*)(wsw + (size_t)blk * WSZ_);
    u32x4* dst = (u32x4*)w_s;
    #pragma unroll
    for (int i = 0; i < 24; ++i) dst[tid + 256 * i] = src[tid + 256 * i];
  }
  __syncthreads();

  const int lane = tid & 63, wave = tid >> 6;
  const int l15 = lane & 15, l4 = lane >> 4;
  const int myn = wave >> 1;            // batch 16-group
  const int kh  = wave & 1;             // K-half
  const int myb = (myn << 4) + l15;
  const int fro = (l4 << 3);
  const int khofs = kh * 256;           // element offset of the K-half
  const int khb = kh * 8;               // frag base of the K-half

  const int cb = tid & 31;
  const int cj = (tid >> 5) * 2;
  const int jg = sub * 16 + cj;

  // in-kernel bias (r9/r10-proven; replaces prep_bias)
  float br0, bz0, bx0, bn0, br1, bz1, bx1, bn1;
  if (l == 0){
    br0 = bhh0g[jg];       bz0 = bhh0g[512 + jg];     bx0 = 0.f; bn0 = bhh0g[1024 + jg];
    br1 = bhh0g[jg + 1];   bz1 = bhh0g[512 + jg + 1]; bx1 = 0.f; bn1 = bhh0g[1024 + jg + 1];
  } else {
    const float* bi = bihrg + (size_t)(l - 1) * G3H_;
    const float* bh = bhhrg + (size_t)(l - 1) * G3H_;
    br0 = bi[jg] + bh[jg];           bz0 = bi[512 + jg] + bh[512 + jg];
    bx0 = bi[1024 + jg];             bn0 = bh[1024 + jg];
    br1 = bi[jg + 1] + bh[jg + 1];   bz1 = bi[512 + jg + 1] + bh[512 + jg + 1];
    bx1 = bi[1024 + jg + 1];         bn1 = bh[1024 + jg + 1];
  }
  float hres0 = 0.f, hres1 = 0.f;

  unsigned short* hTl = hT + (size_t)l * (HRING_ * 32 * 512);
  unsigned short* xTw = xT + (size_t)(l < 4 ? l : 0) * ((size_t)XRING_ * XSLOT_);
  const unsigned short* xTr = xT + (size_t)(l > 0 ? l - 1 : 0) * ((size_t)XRING_ * XSLOT_);
  const int* bp_own = cprog + (l << 5);          // consumers of my x publish here
  int*       bp_pub = cprog + ((l > 0 ? l - 1 : 0) << 5);

  // xp 2-ahead prefetch registers (layer 0 only); chunk-0 gate first
  float era=0,eza=0,ena=0,era1=0,eza1=0,ena1=0;
  float erb=0,ezb=0,enb=0,erb1=0,ezb1=0,enb1=0;
  if (l == 0){
    if (tid == 0){
      int itc = 0;
      while (ld_flag(&gprog[0]) < 768){
        if (++itc > (1 << 20)) break;
        __builtin_amdgcn_s_sleep(8);
      }
    }
    __syncthreads();
    { const float* xq = xp + (size_t)0 * (G3H_ * B_) + cb;
      era=ld_coh_f32(&xq[(size_t)(0*H_+jg)*B_]); era1=ld_coh_f32(&xq[(size_t)(0*H_+jg+1)*B_]);
      eza=ld_coh_f32(&xq[(size_t)(1*H_+jg)*B_]); eza1=ld_coh_f32(&xq[(size_t)(1*H_+jg+1)*B_]);
      ena=ld_coh_f32(&xq[(size_t)(2*H_+jg)*B_]); ena1=ld_coh_f32(&xq[(size_t)(2*H_+jg+1)*B_]); }
    { const float* xq = xp + (size_t)1 * (G3H_ * B_) + cb;
      erb=ld_coh_f32(&xq[(size_t)(0*H_+jg)*B_]); erb1=ld_coh_f32(&xq[(size_t)(0*H_+jg+1)*B_]);
      ezb=ld_coh_f32(&xq[(size_t)(1*H_+jg)*B_]); ezb1=ld_coh_f32(&xq[(size_t)(1*H_+jg+1)*B_]);
      enb=ld_coh_f32(&xq[(size_t)(2*H_+jg)*B_]); enb1=ld_coh_f32(&xq[(size_t)(2*H_+jg+1)*B_]); }
  }

  for (int t = 0; t < T_; ++t){
    const int pb = t & 1;

    // ---- issue x(t) loads (produced >=1 skew-steps ago) ----
    Ufrag xb[8];
    const unsigned short* xs = nullptr;
    if (l > 0){
      xs = xTr + (size_t)(t & (XRING_-1)) * XSLOT_ + (size_t)myb * 512 + khofs + fro;
      #pragma unroll
      for (int j = 0; j < 8; ++j){
        const u64* sp = (const u64*)(xs + (j << 5));
        xb[j].q[0] = ld_coh_u64(sp); xb[j].q[1] = ld_coh_u64(sp + 1);
      }
    }

    // ---- issue all h(t) frag loads (early miss -> cheap; real poll is later) ----
    Ufrag hb[8];
    const unsigned short* hf = hTl + (((size_t)(t & (HRING_-1)) * 32 + myb) << 9) + khofs + fro;
    #pragma unroll
    for (int j = 0; j < 8; ++j){
      const u64* sp = (const u64*)(hf + (j << 5));
      hb[j].q[0] = ld_coh_u64(sp); hb[j].q[1] = ld_coh_u64(sp + 1);
    }

    // ---- producer back-pressure (every 4 steps; proven margins) ----
    if (l < 4 && t && (t & 3) == 0){
      int itc = 0;
      while (true){
        int v = (lane < 32) ? ld_flag(&bp_own[lane]) : 0x7fffffff;
        if (__all(v >= t - 4)) break;
        if (++itc > BCAP) break;
        __builtin_amdgcn_s_sleep(2);
      }
    }

    f32x4 accR = {0.f,0.f,0.f,0.f}, accZ = {0.f,0.f,0.f,0.f};
    f32x4 accN = {0.f,0.f,0.f,0.f}, accX = {0.f,0.f,0.f,0.f};

    // ---- x phase FIRST: fills the h-store visibility window with real work ----
    if (l > 0){
      #pragma unroll
      for (int j = 0; j < 8; ++j){
        int itc = 0;
        while (__any((int)(bad64(xb[j].q[0]) | bad64(xb[j].q[1])))){
          if (++itc > XCAP) break;
          if (itc > 2) __builtin_amdgcn_s_sleep(2);
          const u64* sp = (const u64*)(xs + (j << 5));
          xb[j].q[0] = ld_coh_u64(sp); xb[j].q[1] = ld_coh_u64(sp + 1);
        }
        bf16x8 b  = xb[j].v;
        bf16x8 a0 = *(const bf16x8*)&w_s[(0 * 32 + 16 + khb + j) * 512 + lane * 8];
        bf16x8 a1 = *(const bf16x8*)&w_s[(1 * 32 + 16 + khb + j) * 512 + lane * 8];
        bf16x8 a2 = *(const bf16x8*)&w_s[(2 * 32 + 16 + khb + j) * 512 + lane * 8];
        accR = __builtin_amdgcn_mfma_f32_16x16x32_bf16(a0, b, accR, 0, 0, 0);
        accZ = __builtin_amdgcn_mfma_f32_16x16x32_bf16(a1, b, accZ, 0, 0, 0);
        accX = __builtin_amdgcn_mfma_f32_16x16x32_bf16(a2, b, accX, 0, 0, 0);  // xn
      }
    }

    // ---- h phase: incremental poll-and-consume (wait frag j -> 3 MFMAs) ----
    #pragma unroll
    for (int j = 0; j < 8; ++j){
      int itc = 0;
      while (__any((int)(bad64(hb[j].q[0]) | bad64(hb[j].q[1])))){
        if (++itc > HCAP) break;
        if (itc > 2) __builtin_amdgcn_s_sleep(2);
        const u64* sp = (const u64*)(hf + (j << 5));
        hb[j].q[0] = ld_coh_u64(sp); hb[j].q[1] = ld_coh_u64(sp + 1);
      }
      bf16x8 b  = hb[j].v;
      bf16x8 a0 = *(const bf16x8*)&w_s[(0 * 32 + khb + j) * 512 + lane * 8];
      bf16x8 a1 = *(const bf16x8*)&w_s[(1 * 32 + khb + j) * 512 + lane * 8];
      bf16x8 a2 = *(const bf16x8*)&w_s[(2 * 32 + khb + j) * 512 + lane * 8];
      accR = __builtin_amdgcn_mfma_f32_16x16x32_bf16(a0, b, accR, 0, 0, 0);
      accZ = __builtin_amdgcn_mfma_f32_16x16x32_bf16(a1, b, accZ, 0, 0, 0);
      accN = __builtin_amdgcn_mfma_f32_16x16x32_bf16(a2, b, accN, 0, 0, 0);
    }

    // ---- xp chunk gate + prefetch for t+2 (layer 0) ----
    float erc=0,ezc=0,enc=0,erc1=0,ezc1=0,enc1=0;
    if (l == 0){
      if (((t + 2) & 63) == 0){
        const int ck = ((t + 2) & (T_ - 1)) >> 6;
        if (tid == 0){
          int itc = 0;
          while (ld_flag(&gprog[ck]) < 768){
            if (++itc > (1 << 20)) break;
            __builtin_amdgcn_s_sleep(8);
          }
        }
        __syncthreads();
      }
      const float* xq = xp + (size_t)((t + 2) & (T_ - 1)) * (G3H_ * B_) + cb;
      erc=ld_coh_f32(&xq[(size_t)(0*H_+jg)*B_]); erc1=ld_coh_f32(&xq[(size_t)(0*H_+jg+1)*B_]);
      ezc=ld_coh_f32(&xq[(size_t)(1*H_+jg)*B_]); ezc1=ld_coh_f32(&xq[(size_t)(1*H_+jg+1)*B_]);
      enc=ld_coh_f32(&xq[(size_t)(2*H_+jg)*B_]); enc1=ld_coh_f32(&xq[(size_t)(2*H_+jg+1)*B_]);
    }

    // ---- partials -> p_s[pb] ----
    #pragma unroll
    for (int r = 0; r < 4; ++r){
      int u = l4 * 4 + r;
      p_s[pb][0][myn][kh][u][l15] = accR[r];
      p_s[pb][1][myn][kh][u][l15] = accZ[r];
      p_s[pb][2][myn][kh][u][l15] = accN[r];
      p_s[pb][3][myn][kh][u][l15] = accX[r];
    }
    __syncthreads();

    // ---- combine ----
    {
      const int nt = cb >> 4, bc = cb & 15;
      float rp0 = p_s[pb][0][nt][0][cj][bc]   + p_s[pb][0][nt][1][cj][bc];
      float rp1 = p_s[pb][0][nt][0][cj+1][bc] + p_s[pb][0][nt][1][cj+1][bc];
      float zp0 = p_s[pb][1][nt][0][cj][bc]   + p_s[pb][1][nt][1][cj][bc];
      float zp1 = p_s[pb][1][nt][0][cj+1][bc] + p_s[pb][1][nt][1][cj+1][bc];
      float hp0 = p_s[pb][2][nt][0][cj][bc]   + p_s[pb][2][nt][1][cj][bc];
      float hp1 = p_s[pb][2][nt][0][cj+1][bc] + p_s[pb][2][nt][1][cj+1][bc];
      float xq0 = p_s[pb][3][nt][0][cj][bc]   + p_s[pb][3][nt][1][cj][bc];
      float xq1 = p_s[pb][3][nt][0][cj+1][bc] + p_s[pb][3][nt][1][cj+1][bc];
      float r0 = 1.f / (1.f + __expf(-(rp0 + era  + br0)));
      float r1 = 1.f / (1.f + __expf(-(rp1 + era1 + br1)));
      float z0 = 1.f / (1.f + __expf(-(zp0 + eza  + bz0)));
      float z1 = 1.f / (1.f + __expf(-(zp1 + eza1 + bz1)));
      float nx0 = (l > 0) ? (xq0 + bx0) : ena;
      float nx1 = (l > 0) ? (xq1 + bx1) : ena1;
      float e0 = __expf(2.f * (nx0 + r0 * (hp0 + bn0)));
      float e1 = __expf(2.f * (nx1 + r1 * (hp1 + bn1)));
      float n0 = (e0 - 1.f) / (e0 + 1.f);
      float n1 = (e1 - 1.f) / (e1 + 1.f);
      float h0 = (1.f - z0) * n0 + z0 * hres0; hres0 = h0;
      float h1 = (1.f - z1) * n1 + z1 * hres1; hres1 = h1;
      unsigned int pk = (unsigned int)f2bf(h0) | ((unsigned int)f2bf(h1) << 16);

      // h data first (peers are waiting on it), then x data, then sentinels
      st_coh_u32(hTl + (((size_t)((t + 1) & (HRING_-1)) * 32 + cb) << 9) + jg, pk);
      if (l < 4)
        st_coh_u32(xTw + (size_t)(t & (XRING_-1)) * XSLOT_ + (size_t)cb * 512 + jg, pk);
      else
        *(unsigned int*)&xout[((size_t)cb * T_ + t) * H_ + jg] = pk;   // plain (r8)
      st_coh_u32(hTl + (((size_t)((t + 4) & (HRING_-1)) * 32 + cb) << 9) + jg, SENT32);
      if (l < 4)
        st_coh_u32(xTw + (size_t)((t + 16) & (XRING_-1)) * XSLOT_ + (size_t)cb * 512 + jg, SENT32);

      // consumer progress publish (every 4 steps; proven)
      if (l > 0 && (t & 3) == 3 && tid == 0) st_flag(&bp_pub[sub], t);

      // rotate xp prefetch regs
      era = erb; eza = ezb; ena = enb; era1 = erb1; eza1 = ezb1; ena1 = enb1;
      erb = erc; ezb = ezc; enb = enc; erb1 = erc1; ezb1 = ezc1; enb1 = enc1;
    }
  }
}

extern "C" void kernel_launch(void* const* d_in, const int* in_sizes, int n_in,
                              void* d_out, int out_size, void* d_ws, size_t ws_size,
                              hipStream_t stream){
  (void)in_sizes; (void)n_in; (void)out_size; (void)ws_size;
  const int*   note  = (const int*)d_in[0];
  const int*   chord = (const int*)d_in[1];
  const float* ctab  = (const float*)d_in[2];
  const float* ntab  = (const float*)d_in[3];
  const float* wih0  = (const float*)d_in[4];
  const float* whh0  = (const float*)d_in[5];
  const float* bih0  = (const float*)d_in[6];
  const float* bhh0  = (const float*)d_in[7];
  const float* wihr  = (const float*)d_in[8];
  const float* whhr  = (const float*)d_in[9];
  const float* bihr  = (const float*)d_in[10];
  const float* bhhr  = (const float*)d_in[11];
  const float* fcw   = (const float*)d_in[12];
  const float* fcb   = (const float*)d_in[13];
  float* out = (float*)d_out;

  char* ws = (char*)d_ws;
  size_t off = 0;
  auto alloc = [&](size_t bytes)->char*{
    char* p = ws + off; off = (off + bytes + 255) & ~(size_t)255; return p;
  };
  int*            cprog   = (int*)alloc(160 * sizeof(int));
  int*            gprog   = (int*)alloc(8 * sizeof(int));
  float*          xp      = (float*)alloc((size_t)BT_ * G3H_ * 4);        // 100.66 MB
  unsigned short* wsw     = (unsigned short*)alloc((size_t)NBF_ * WSZ_ * 2); // 15.73 MB
  unsigned short* fcw_b   = (unsigned short*)alloc((size_t)CV_ * H_ * 2); // 0.15 MB
  unsigned short* xout    = (unsigned short*)alloc((size_t)BT_ * H_ * 2); // 16.78 MB
  unsigned short* x0      = (unsigned short*)alloc((size_t)BT_ * K0_ * 2);// 33.55 MB
  unsigned short* wih0_b  = (unsigned short*)alloc((size_t)G3H_ * K0_ * 2);// 3.15 MB
  const size_t hT_bytes = (size_t)5 * HRING_ * 32 * 512 * 2;              // 2.62 MB
  const size_t xT_bytes = (size_t)4 * XRING_ * XSLOT_ * 2;                // 4.19 MB
  unsigned short* hT      = (unsigned short*)alloc(hT_bytes);
  unsigned short* xT      = (unsigned short*)alloc(xT_bytes);
  // total ~177 MB? no: 100.7+15.7+0.15+16.8+33.6+3.2+2.6+4.2 = 176.9 -> trim:
  // xp (100.66) dominates; proven budget >=172.5 (r0 used 172.5). Overlap x0 with
  // nothing needed: x0 is consumed only by xp-GEMM inside the fused kernel, and
  // wsw only by GRU role -- both must coexist. Reuse fcw_b region? negligible.
  // r0's footprint proof: 172.5 MB passed. Keep within by overlapping xT with
  // nothing -- actual sum = 176.9 MB. To be safe, carve hT/xT from d_out scratch
  // is unsafe (FC writes out). Instead overlap wih0_b (dead after xp-GEMM? no --
  // used throughout fused kernel). Shave via x0: x0 dead after fused kernel but
  // coexists. Use ws_size headroom: harness workspace is >= 256 MB in practice;
  // r1 used ~202 MB successfully? r1 failed. r0 proved 172.5. Trim 4.4 MB:
  // fcw_b moved into gap: drop separate alloc by overlaying onto tail of xp's
  // 256-byte alignment waste is insufficient. Simplest: shrink XRING_ would change
  // protocol. Accept 176.9 MB -- within typical 192 MB+ workspaces and only 4.4 MB
  // over the proven point; r8 itself ran at 171 MB + wsw? r8: cprog+gprog+xp+fcw_b+
  // xout+x0+wih0_b+hT+xT = 161.2 MB and separately wsw 15.7 => 176.9 MB total,
  // and r8 PASSED with this exact footprint (wsw was allocated there too).

  hipMemsetAsync(cprog, 0, 160 * sizeof(int), stream);
  hipMemsetAsync(gprog, 0, 8 * sizeof(int), stream);
  hipMemsetAsync(hT, 0x7F, hT_bytes, stream);
  for (int ll = 0; ll < 5; ++ll)   // slot 0 = h(0) = zeros
    hipMemsetAsync(hT + (size_t)ll * (HRING_ * 32 * 512), 0, 32 * 512 * 2, stream);
  hipMemsetAsync(xT, 0x7F, xT_bytes, stream);

  { int n = G3H_ * K0_; convert_bf16<<<(n + 255) / 256, 256, 0, stream>>>(wih0, wih0_b, n); }
  { int n = CV_ * H_;   convert_bf16<<<(n + 255) / 256, 256, 0, stream>>>(fcw, fcw_b, n); }
  { int n = NBF_ * WSZ_;
    prep_wfrag<<<(n + 255) / 256, 256, 0, stream>>>(whh0, whhr, wihr, wsw, n); }

  emb_kernel<<<BT_, 64, 0, stream>>>(note, chord, ctab, ntab, x0);

  // fused: 160 GRU + 6144 xp-GEMM (chunk-major) blocks in one launch
  gru_fused<<<NBF_ + GXB_, 256, 0, stream>>>(
      xp, wsw, hT, xT, xout, cprog, x0, wih0_b, bih0, gprog,
      bhh0, bihr, bhhr);

  // FC: out = xout @ fcw^T + fcb  (separate launch — r8 structure)
  gemm_bt<<<dim3((CV_ + 63) / 64, BT_ / 64), 256, 0, stream>>>(
      xout, fcw_b, fcb, out, BT_, CV_, H_, 0);
}